// Round 2
// baseline (185.861 us; speedup 1.0000x reference)
//
#include <hip/hip_runtime.h>

#define Nn 1024
#define Cc 256
#define Hh 4
#define Dd 64
#define HD 256
#define LOG2E 1.4426950408889634f

typedef unsigned short u16;
typedef unsigned int u32;
typedef unsigned long long u64;
typedef unsigned char u8;
typedef __bf16 bf16x8 __attribute__((ext_vector_type(8)));
typedef float f32x4 __attribute__((ext_vector_type(4)));
typedef u16 u16x8 __attribute__((ext_vector_type(8)));

__device__ __forceinline__ float bf2f(u16 v) {
    return __builtin_bit_cast(float, (u32)v << 16);
}
__device__ __forceinline__ u16 f2bf(float f) {
    u32 u = __builtin_bit_cast(u32, f);
    return (u16)((u + 0x7fffu + ((u >> 16) & 1u)) >> 16);
}
__device__ __forceinline__ float leaky(float s) {
    return fmaxf(s, 0.2f * s);
}

// ---- k0: W (C x HD) fp32 -> WT_hi/WT_lo (HD x C) bf16 split ----
__global__ void k_prep_w(const float* __restrict__ W, u16* __restrict__ WTh,
                         u16* __restrict__ WTl) {
    int c = blockIdx.x;          // 0..255 (row of W)
    int t = threadIdx.x;         // 0..255 (col of W)
    float v = W[c * HD + t];
    u16 hi = f2bf(v);
    float lo = v - bf2f(hi);
    WTh[t * Cc + c] = hi;
    WTl[t * Cc + c] = f2bf(lo);
}

// ---- k1: Wx = x @ W via split-bf16 MFMA; store WxTbf[b,h,d,n] bf16;
//          fused epilogue computes exact fp32 ei/ej. ----
__global__ __launch_bounds__(256) void k_gemm_xw(const float* __restrict__ x,
        const u16* __restrict__ WTh, const u16* __restrict__ WTl,
        const float* __restrict__ a, u16* __restrict__ WxTbf,
        float* __restrict__ ei, float* __restrict__ ej) {
    int wave = blockIdx.x * 4 + (threadIdx.x >> 6);
    int lane = threadIdx.x & 63;
    int row_tile = wave >> 2;        // 0..511 over 8192 rows
    int h = wave & 3;                // 64-col group == head
    int m0 = row_tile * 16;
    int b = m0 >> 10;
    int nloc0 = m0 & 1023;
    int c15 = lane & 15;
    int quad = lane >> 4;

    f32x4 acc[4] = {};
    const float* xrow = x + (size_t)(m0 + c15) * Cc + quad * 8;
    #pragma unroll
    for (int k0 = 0; k0 < Cc; k0 += 32) {
        float4 xv0 = *reinterpret_cast<const float4*>(xrow + k0);
        float4 xv1 = *reinterpret_cast<const float4*>(xrow + k0 + 4);
        float xv[8] = {xv0.x, xv0.y, xv0.z, xv0.w, xv1.x, xv1.y, xv1.z, xv1.w};
        u16x8 xh, xl;
        #pragma unroll
        for (int i = 0; i < 8; ++i) {
            u16 hb = f2bf(xv[i]);
            xh[i] = hb;
            xl[i] = f2bf(xv[i] - bf2f(hb));
        }
        bf16x8 ah = __builtin_bit_cast(bf16x8, xh);
        bf16x8 al = __builtin_bit_cast(bf16x8, xl);
        #pragma unroll
        for (int t = 0; t < 4; ++t) {
            const u16* wb = WTh + (size_t)(h * 64 + t * 16 + c15) * Cc + k0 + quad * 8;
            const u16* wl = WTl + (size_t)(h * 64 + t * 16 + c15) * Cc + k0 + quad * 8;
            bf16x8 bh = *reinterpret_cast<const bf16x8*>(wb);
            bf16x8 bl = *reinterpret_cast<const bf16x8*>(wl);
            acc[t] = __builtin_amdgcn_mfma_f32_16x16x32_bf16(ah, bh, acc[t], 0, 0, 0);
            acc[t] = __builtin_amdgcn_mfma_f32_16x16x32_bf16(al, bh, acc[t], 0, 0, 0);
            acc[t] = __builtin_amdgcn_mfma_f32_16x16x32_bf16(ah, bl, acc[t], 0, 0, 0);
        }
    }
    int bh = b * Hh + h;
    // store bf16 WxT: value acc[t][r] = Wx[n = nloc0+quad*4+r][d = t*16+c15]
    #pragma unroll
    for (int t = 0; t < 4; ++t) {
        int d = t * 16 + c15;
        size_t base = ((size_t)bh * Dd + d) * Nn + nloc0 + quad * 4;
        u32 lo = (u32)f2bf(acc[t][0]) | ((u32)f2bf(acc[t][1]) << 16);
        u32 hi = (u32)f2bf(acc[t][2]) | ((u32)f2bf(acc[t][3]) << 16);
        uint2 pk; pk.x = lo; pk.y = hi;
        *reinterpret_cast<uint2*>(WxTbf + base) = pk;
    }
    // exact ei/ej from fp32 acc: reduce over d (4 t-slots + 16 lanes of group)
    float ai[4], aj[4];
    #pragma unroll
    for (int t = 0; t < 4; ++t) {
        ai[t] = a[h * 2 * Dd + t * 16 + c15];
        aj[t] = a[h * 2 * Dd + Dd + t * 16 + c15];
    }
    #pragma unroll
    for (int r = 0; r < 4; ++r) {
        float si = acc[0][r] * ai[0] + acc[1][r] * ai[1] + acc[2][r] * ai[2] + acc[3][r] * ai[3];
        float sj = acc[0][r] * aj[0] + acc[1][r] * aj[1] + acc[2][r] * aj[2] + acc[3][r] * aj[3];
        #pragma unroll
        for (int off = 1; off < 16; off <<= 1) {
            si += __shfl_xor(si, off);
            sj += __shfl_xor(sj, off);
        }
        if (c15 == 0) {
            int n = nloc0 + quad * 4 + r;
            ei[(size_t)bh * Nn + n] = si;
            ej[(size_t)bh * Nn + n] = sj;
        }
    }
}

// ---- k2: per (b,n): softmax stats m,l per h + adjacency bitmask ----
__global__ __launch_bounds__(256) void k_stats(const float* __restrict__ adj,
        const float* __restrict__ ei, const float* __restrict__ ej,
        float* __restrict__ mrow, float* __restrict__ lrow, u64* __restrict__ bm) {
    int bn = blockIdx.x;             // b*1024 + n
    int b = bn >> 10;
    int n = bn & 1023;
    int tid = threadIdx.x;
    int wid = tid >> 6, lane = tid & 63;

    float eih[Hh];
    #pragma unroll
    for (int h = 0; h < Hh; ++h) eih[h] = ei[(size_t)(b * Hh + h) * Nn + n];
    float mh[Hh], lh[Hh];
    #pragma unroll
    for (int h = 0; h < Hh; ++h) { mh[h] = -1.0e30f; lh[h] = 0.f; }

    const float* adjrow = adj + (size_t)bn * Nn;
    #pragma unroll
    for (int k = 0; k < 4; ++k) {
        int j = k * 256 + tid;
        u32 av = __builtin_bit_cast(u32, adjrow[j]);
        bool un = (av != 0) || (j == n);
        u64 bal = __ballot(un);
        if (lane == 0) bm[(size_t)bn * 16 + k * 4 + wid] = bal;
        if (un) {
            #pragma unroll
            for (int h = 0; h < Hh; ++h) {
                float s = leaky(eih[h] + ej[(size_t)(b * Hh + h) * Nn + j]);
                float M = fmaxf(mh[h], s);
                lh[h] = lh[h] * exp2f((mh[h] - M) * LOG2E) + exp2f((s - M) * LOG2E);
                mh[h] = M;
            }
        }
    }
    #pragma unroll
    for (int off = 32; off > 0; off >>= 1) {
        #pragma unroll
        for (int h = 0; h < Hh; ++h) {
            float mo = __shfl_xor(mh[h], off);
            float lo = __shfl_xor(lh[h], off);
            float M = fmaxf(mh[h], mo);
            lh[h] = lh[h] * exp2f((mh[h] - M) * LOG2E) + lo * exp2f((mo - M) * LOG2E);
            mh[h] = M;
        }
    }
    __shared__ float sm[4][Hh], sl[4][Hh];
    if (lane == 0) {
        #pragma unroll
        for (int h = 0; h < Hh; ++h) { sm[wid][h] = mh[h]; sl[wid][h] = lh[h]; }
    }
    __syncthreads();
    if (tid < Hh) {
        int h = tid;
        float M = sm[0][h], L = sl[0][h];
        #pragma unroll
        for (int w = 1; w < 4; ++w) {
            float mo = sm[w][h], lo = sl[w][h];
            float Mn = fmaxf(M, mo);
            L = L * exp2f((M - Mn) * LOG2E) + lo * exp2f((mo - Mn) * LOG2E);
            M = Mn;
        }
        mrow[(size_t)(b * Hh + h) * Nn + n] = M;
        lrow[(size_t)(b * Hh + h) * Nn + n] = L;
    }
}

// ---- k3: out = softmax(e) @ Wx per (b,h); MFMA over j; fp32 out ----
__global__ __launch_bounds__(256) void k_attn(const u64* __restrict__ bm,
        const u16* __restrict__ WxTbf, const float* __restrict__ ei,
        const float* __restrict__ ejp, const float* __restrict__ mrow,
        const float* __restrict__ lrow, float* __restrict__ out) {
    int wave = blockIdx.x * 4 + (threadIdx.x >> 6);
    int lane = threadIdx.x & 63;
    int bh = wave >> 6;        // 0..31
    int ntile = wave & 63;     // 0..63
    int b = bh >> 2, h = bh & 3;
    int n0 = ntile * 16;
    int col = lane & 15;
    int quad = lane >> 4;

    int nrow = n0 + col;       // A-fragment row (m) owned by this lane
    float ei_r = ei[(size_t)bh * Nn + nrow];
    float m_r  = mrow[(size_t)bh * Nn + nrow];

    const u8* mbrow = (const u8*)(bm + (size_t)(b * Nn + nrow) * 16);
    const float* ejrow = ejp + (size_t)bh * Nn + quad * 8;
    const u16* wxbase = WxTbf + (size_t)bh * Dd * Nn + quad * 8;

    f32x4 acc[4] = {};
    for (int j0 = 0; j0 < Nn; j0 += 32) {
        u8 mbits = mbrow[(j0 >> 3) + quad];
        float4 ej0 = *reinterpret_cast<const float4*>(ejrow + j0);
        float4 ej1 = *reinterpret_cast<const float4*>(ejrow + j0 + 4);
        float ejv[8] = {ej0.x, ej0.y, ej0.z, ej0.w, ej1.x, ej1.y, ej1.z, ej1.w};
        u16x8 au;
        #pragma unroll
        for (int i = 0; i < 8; ++i) {
            float s = leaky(ei_r + ejv[i]);
            float p = exp2f((s - m_r) * LOG2E);
            au[i] = ((mbits >> i) & 1) ? f2bf(p) : (u16)0;
        }
        bf16x8 afr = __builtin_bit_cast(bf16x8, au);
        #pragma unroll
        for (int t = 0; t < 4; ++t) {
            bf16x8 bfr = *reinterpret_cast<const bf16x8*>(
                wxbase + (size_t)(t * 16 + col) * Nn + j0);
            acc[t] = __builtin_amdgcn_mfma_f32_16x16x32_bf16(afr, bfr, acc[t], 0, 0, 0);
        }
    }
    // epilogue: C/D col = lane&15 (=d within tile), row = quad*4 + r
    #pragma unroll
    for (int r = 0; r < 4; ++r) {
        int nr = n0 + quad * 4 + r;
        float inv = 1.0f / lrow[(size_t)bh * Nn + nr];
        size_t obase = ((size_t)(b * Nn + nr)) * HD + h * Dd;
        #pragma unroll
        for (int t = 0; t < 4; ++t) {
            out[obase + t * 16 + col] = acc[t][r] * inv;
        }
    }
}

extern "C" void kernel_launch(void* const* d_in, const int* in_sizes, int n_in,
                              void* d_out, int out_size, void* d_ws, size_t ws_size,
                              hipStream_t stream) {
    const float* x   = (const float*)d_in[0];   // (8,1024,256) fp32
    const float* adj = (const float*)d_in[1];   // (8,1024,1024) fp32
    const float* W   = (const float*)d_in[2];   // (256,256) fp32
    const float* a   = (const float*)d_in[3];   // (1,4,128) fp32
    float* out = (float*)d_out;                 // (8,1024,256) fp32

    char* ws = (char*)d_ws;
    u16*   WTh   = (u16*)(ws);                          // 128 KiB
    u16*   WTl   = (u16*)(ws + (128u << 10));           // 128 KiB
    u16*   WxTbf = (u16*)(ws + (256u << 10));           // 4 MiB  (B,H,D,N)
    float* ei    = (float*)(ws + (256u << 10) + (4u << 20));                 // 128 KiB
    float* ej    = (float*)(ws + (384u << 10) + (4u << 20));                 // 128 KiB
    float* mrow  = (float*)(ws + (512u << 10) + (4u << 20));                 // 128 KiB
    float* lrow  = (float*)(ws + (640u << 10) + (4u << 20));                 // 128 KiB
    u64*   bm    = (u64*)(ws + (768u << 10) + (4u << 20));                   // 1 MiB

    k_prep_w<<<256, 256, 0, stream>>>(W, WTh, WTl);
    k_gemm_xw<<<512, 256, 0, stream>>>(x, WTh, WTl, a, WxTbf, ei, ej);
    k_stats<<<8192, 256, 0, stream>>>(adj, ei, ej, mrow, lrow, bm);
    k_attn<<<512, 256, 0, stream>>>(bm, WxTbf, ei, ej, mrow, lrow, out);
}

// Round 3
// 127.627 us; speedup vs baseline: 1.4563x; 1.4563x over previous
//
#include <hip/hip_runtime.h>

#define Nn 1024
#define Cc 256
#define Hh 4
#define Dd 64
#define HD 256
#define LOG2E 1.4426950408889634f

typedef unsigned short u16;
typedef unsigned int u32;
typedef unsigned long long u64;
typedef unsigned char u8;
typedef __bf16 bf16x8 __attribute__((ext_vector_type(8)));
typedef float f32x4 __attribute__((ext_vector_type(4)));
typedef u16 u16x8 __attribute__((ext_vector_type(8)));

__device__ __forceinline__ float bf2f(u16 v) {
    return __builtin_bit_cast(float, (u32)v << 16);
}
__device__ __forceinline__ u16 f2bf(float f) {
    u32 u = __builtin_bit_cast(u32, f);
    return (u16)((u + 0x7fffu + ((u >> 16) & 1u)) >> 16);
}
__device__ __forceinline__ float leaky(float s) {
    return fmaxf(s, 0.2f * s);
}

// ---- k0: W (C x HD) fp32 -> WT_hi/WT_lo (HD x C) bf16 split ----
__global__ void k_prep_w(const float* __restrict__ W, u16* __restrict__ WTh,
                         u16* __restrict__ WTl) {
    int c = blockIdx.x;          // 0..255 (row of W)
    int t = threadIdx.x;         // 0..255 (col of W)
    float v = W[c * HD + t];
    u16 hi = f2bf(v);
    float lo = v - bf2f(hi);
    WTh[t * Cc + c] = hi;
    WTl[t * Cc + c] = f2bf(lo);
}

// ---- k1: Wx = x @ W via split-bf16 MFMA.
//      Stores WxTt in MFMA-B tile layout:
//        offset(bh, n, d) = bh*65536 + (n>>5)*2048 + (d>>4)*512
//                           + ((n>>3)&3)*128 + (d&15)*8 + (n&7)
//      Fused epilogue computes exact fp32 ei/ej. ----
__global__ __launch_bounds__(256) void k_gemm_xw(const float* __restrict__ x,
        const u16* __restrict__ WTh, const u16* __restrict__ WTl,
        const float* __restrict__ a, u16* __restrict__ WxTt,
        float* __restrict__ ei, float* __restrict__ ej) {
    int wave = blockIdx.x * 4 + (threadIdx.x >> 6);
    int lane = threadIdx.x & 63;
    int row_tile = wave >> 2;        // 0..511 over 8192 rows
    int h = wave & 3;                // 64-col group == head
    int m0 = row_tile * 16;
    int b = m0 >> 10;
    int nloc0 = m0 & 1023;
    int c15 = lane & 15;
    int quad = lane >> 4;

    f32x4 acc[4] = {};
    const float* xrow = x + (size_t)(m0 + c15) * Cc + quad * 8;
    #pragma unroll
    for (int k0 = 0; k0 < Cc; k0 += 32) {
        float4 xv0 = *reinterpret_cast<const float4*>(xrow + k0);
        float4 xv1 = *reinterpret_cast<const float4*>(xrow + k0 + 4);
        float xv[8] = {xv0.x, xv0.y, xv0.z, xv0.w, xv1.x, xv1.y, xv1.z, xv1.w};
        u16x8 xh, xl;
        #pragma unroll
        for (int i = 0; i < 8; ++i) {
            u16 hb = f2bf(xv[i]);
            xh[i] = hb;
            xl[i] = f2bf(xv[i] - bf2f(hb));
        }
        bf16x8 ah = __builtin_bit_cast(bf16x8, xh);
        bf16x8 al = __builtin_bit_cast(bf16x8, xl);
        #pragma unroll
        for (int t = 0; t < 4; ++t) {
            const u16* wb = WTh + (size_t)(h * 64 + t * 16 + c15) * Cc + k0 + quad * 8;
            const u16* wl = WTl + (size_t)(h * 64 + t * 16 + c15) * Cc + k0 + quad * 8;
            bf16x8 bh = *reinterpret_cast<const bf16x8*>(wb);
            bf16x8 bl = *reinterpret_cast<const bf16x8*>(wl);
            acc[t] = __builtin_amdgcn_mfma_f32_16x16x32_bf16(ah, bh, acc[t], 0, 0, 0);
            acc[t] = __builtin_amdgcn_mfma_f32_16x16x32_bf16(al, bh, acc[t], 0, 0, 0);
            acc[t] = __builtin_amdgcn_mfma_f32_16x16x32_bf16(ah, bl, acc[t], 0, 0, 0);
        }
    }
    int bh = b * Hh + h;
    // acc[t][r] = Wx[n = nloc0 + quad*4 + r][d = t*16 + c15]
    // tile store: n_base = nloc0 + quad*4 (r=0..3 consecutive => contiguous i)
    int n_base = nloc0 + quad * 4;
    int chunk = nloc0 >> 5;
    int jq = ((n_base >> 3) & 3);
    int ii = n_base & 7;             // 0 or 4
    size_t tb = (size_t)bh * 65536 + chunk * 2048 + jq * 128 + c15 * 8 + ii;
    #pragma unroll
    for (int t = 0; t < 4; ++t) {
        u32 lo = (u32)f2bf(acc[t][0]) | ((u32)f2bf(acc[t][1]) << 16);
        u32 hi = (u32)f2bf(acc[t][2]) | ((u32)f2bf(acc[t][3]) << 16);
        uint2 pk; pk.x = lo; pk.y = hi;
        *reinterpret_cast<uint2*>(WxTt + tb + t * 512) = pk;
    }
    // exact ei/ej from fp32 acc: reduce over d (4 t-slots + 16 lanes)
    float ai[4], aj[4];
    #pragma unroll
    for (int t = 0; t < 4; ++t) {
        ai[t] = a[h * 2 * Dd + t * 16 + c15];
        aj[t] = a[h * 2 * Dd + Dd + t * 16 + c15];
    }
    #pragma unroll
    for (int r = 0; r < 4; ++r) {
        float si = acc[0][r] * ai[0] + acc[1][r] * ai[1] + acc[2][r] * ai[2] + acc[3][r] * ai[3];
        float sj = acc[0][r] * aj[0] + acc[1][r] * aj[1] + acc[2][r] * aj[2] + acc[3][r] * aj[3];
        #pragma unroll
        for (int off = 1; off < 16; off <<= 1) {
            si += __shfl_xor(si, off);
            sj += __shfl_xor(sj, off);
        }
        if (c15 == 0) {
            int n = nloc0 + quad * 4 + r;
            ei[(size_t)bh * Nn + n] = si;
            ej[(size_t)bh * Nn + n] = sj;
        }
    }
}

// ---- k2: adjacency byte-mask (incl. diagonal). bm[bn][128] bytes ----
__global__ __launch_bounds__(256) void k_bitmask(const float* __restrict__ adj,
                                                 u8* __restrict__ bm) {
    int idx = blockIdx.x * 256 + threadIdx.x;   // 0 .. 1048575
    int bn = idx >> 7;
    int byteidx = idx & 127;
    int n = bn & 1023;
    const float* p = adj + ((size_t)bn << 10) + (byteidx << 3);
    float4 v0 = *reinterpret_cast<const float4*>(p);
    float4 v1 = *reinterpret_cast<const float4*>(p + 4);
    u32 bits = 0;
    bits |= (__builtin_bit_cast(u32, v0.x) != 0u) ? 1u : 0u;
    bits |= (__builtin_bit_cast(u32, v0.y) != 0u) ? 2u : 0u;
    bits |= (__builtin_bit_cast(u32, v0.z) != 0u) ? 4u : 0u;
    bits |= (__builtin_bit_cast(u32, v0.w) != 0u) ? 8u : 0u;
    bits |= (__builtin_bit_cast(u32, v1.x) != 0u) ? 16u : 0u;
    bits |= (__builtin_bit_cast(u32, v1.y) != 0u) ? 32u : 0u;
    bits |= (__builtin_bit_cast(u32, v1.z) != 0u) ? 64u : 0u;
    bits |= (__builtin_bit_cast(u32, v1.w) != 0u) ? 128u : 0u;
    if ((n >> 3) == byteidx) bits |= 1u << (n & 7);
    bm[idx] = (u8)bits;
}

// ---- k3: out = softmax(e) @ Wx per (b,h); no max-subtraction;
//          l accumulated in-register during the K-loop. ----
__global__ __launch_bounds__(256) void k_attn(const u8* __restrict__ bm,
        const u16* __restrict__ WxTt, const float* __restrict__ ei,
        const float* __restrict__ ejp, float* __restrict__ out) {
    int wave = blockIdx.x * 4 + (threadIdx.x >> 6);
    int lane = threadIdx.x & 63;
    int bh = wave >> 6;        // 0..31
    int ntile = wave & 63;     // 0..63
    int b = bh >> 2, h = bh & 3;
    int n0 = ntile * 16;
    int col = lane & 15;
    int quad = lane >> 4;

    int nrow = n0 + col;       // A-fragment row (m) owned by this lane
    float ei_r = ei[(size_t)bh * Nn + nrow];

    const u8* mbrow = bm + ((size_t)(b * Nn + nrow)) * 128;
    const float* ejrow = ejp + (size_t)bh * Nn + quad * 8;
    const u16* wxplane = WxTt + (size_t)bh * 65536 + lane * 8;

    f32x4 acc[4] = {};
    float lsum = 0.f;
    for (int j0 = 0; j0 < Nn; j0 += 32) {
        u32 mb32 = *reinterpret_cast<const u32*>(mbrow + (j0 >> 3));
        u32 mbits = (mb32 >> (quad * 8)) & 0xffu;
        float4 ej0 = *reinterpret_cast<const float4*>(ejrow + j0);
        float4 ej1 = *reinterpret_cast<const float4*>(ejrow + j0 + 4);
        float ejv[8] = {ej0.x, ej0.y, ej0.z, ej0.w, ej1.x, ej1.y, ej1.z, ej1.w};
        u16x8 au;
        #pragma unroll
        for (int i = 0; i < 8; ++i) {
            float s = leaky(ei_r + ejv[i]);
            float p = exp2f(s * LOG2E);
            p = ((mbits >> i) & 1u) ? p : 0.f;
            lsum += p;
            au[i] = f2bf(p);
        }
        bf16x8 afr = __builtin_bit_cast(bf16x8, au);
        const u16* bbase = wxplane + (j0 >> 5) * 2048;
        #pragma unroll
        for (int t = 0; t < 4; ++t) {
            bf16x8 bfr = *reinterpret_cast<const bf16x8*>(bbase + t * 512);
            acc[t] = __builtin_amdgcn_mfma_f32_16x16x32_bf16(afr, bfr, acc[t], 0, 0, 0);
        }
    }
    // reduce l across the 4 quads (same col => same row)
    lsum += __shfl_xor(lsum, 16);
    lsum += __shfl_xor(lsum, 32);
    // epilogue: C/D col = lane&15 (=d within tile), row = quad*4 + r
    #pragma unroll
    for (int r = 0; r < 4; ++r) {
        int rloc = quad * 4 + r;
        float lv = __shfl(lsum, rloc);   // lane rloc (<16) holds l[n0+rloc]
        float inv = 1.0f / lv;
        int nr = n0 + rloc;
        size_t obase = ((size_t)(b * Nn + nr)) * HD + h * Dd;
        #pragma unroll
        for (int t = 0; t < 4; ++t) {
            out[obase + t * 16 + col] = acc[t][r] * inv;
        }
    }
}

extern "C" void kernel_launch(void* const* d_in, const int* in_sizes, int n_in,
                              void* d_out, int out_size, void* d_ws, size_t ws_size,
                              hipStream_t stream) {
    const float* x   = (const float*)d_in[0];   // (8,1024,256) fp32
    const float* adj = (const float*)d_in[1];   // (8,1024,1024) fp32
    const float* W   = (const float*)d_in[2];   // (256,256) fp32
    const float* a   = (const float*)d_in[3];   // (1,4,128) fp32
    float* out = (float*)d_out;                 // (8,1024,256) fp32

    char* ws = (char*)d_ws;
    u16*   WTh  = (u16*)(ws);                                   // 128 KiB
    u16*   WTl  = (u16*)(ws + (128u << 10));                    // 128 KiB
    u16*   WxTt = (u16*)(ws + (256u << 10));                    // 4 MiB tile layout
    float* ei   = (float*)(ws + (256u << 10) + (4u << 20));     // 128 KiB
    float* ej   = (float*)(ws + (384u << 10) + (4u << 20));     // 128 KiB
    u8*    bm   = (u8*)(ws + (512u << 10) + (4u << 20));        // 1 MiB

    k_prep_w<<<256, 256, 0, stream>>>(W, WTh, WTl);
    k_gemm_xw<<<512, 256, 0, stream>>>(x, WTh, WTl, a, WxTt, ei, ej);
    k_bitmask<<<4096, 256, 0, stream>>>(adj, bm);
    k_attn<<<512, 256, 0, stream>>>(bm, WxTt, ei, ej, out);
}

// Round 4
// 124.935 us; speedup vs baseline: 1.4877x; 1.0215x over previous
//
#include <hip/hip_runtime.h>

#define Nn 1024
#define Cc 256
#define Hh 4
#define Dd 64
#define HD 256
#define LOG2E 1.4426950408889634f

typedef unsigned short u16;
typedef unsigned int u32;
typedef unsigned long long u64;
typedef unsigned char u8;
typedef __bf16 bf16x8 __attribute__((ext_vector_type(8)));
typedef float f32x4 __attribute__((ext_vector_type(4)));
typedef u16 u16x8 __attribute__((ext_vector_type(8)));
typedef u32 u32x4 __attribute__((ext_vector_type(4)));

__device__ __forceinline__ float bf2f(u16 v) {
    return __builtin_bit_cast(float, (u32)v << 16);
}
__device__ __forceinline__ u16 f2bf(float f) {
    u32 u = __builtin_bit_cast(u32, f);
    return (u16)((u + 0x7fffu + ((u >> 16) & 1u)) >> 16);
}
__device__ __forceinline__ float fast_exp2(float x) {
#if __has_builtin(__builtin_amdgcn_exp2f)
    return __builtin_amdgcn_exp2f(x);
#else
    float r; asm("v_exp_f32 %0, %1" : "=v"(r) : "v"(x)); return r;
#endif
}

// ---- k0: fused adjacency byte-mask + W split-transpose ----
__global__ __launch_bounds__(256) void k_bitmask_prep(const float* __restrict__ adj,
        u8* __restrict__ bm, const float* __restrict__ W,
        u16* __restrict__ WTh, u16* __restrict__ WTl) {
    int idx = blockIdx.x * 256 + threadIdx.x;   // 0 .. 1048575
    int bn = idx >> 7;
    int byteidx = idx & 127;
    int n = bn & 1023;
    const float* p = adj + ((size_t)bn << 10) + (byteidx << 3);
    float4 v0 = *reinterpret_cast<const float4*>(p);
    float4 v1 = *reinterpret_cast<const float4*>(p + 4);
    u32 bits = 0;
    bits |= (__builtin_bit_cast(u32, v0.x) != 0u) ? 1u : 0u;
    bits |= (__builtin_bit_cast(u32, v0.y) != 0u) ? 2u : 0u;
    bits |= (__builtin_bit_cast(u32, v0.z) != 0u) ? 4u : 0u;
    bits |= (__builtin_bit_cast(u32, v0.w) != 0u) ? 8u : 0u;
    bits |= (__builtin_bit_cast(u32, v1.x) != 0u) ? 16u : 0u;
    bits |= (__builtin_bit_cast(u32, v1.y) != 0u) ? 32u : 0u;
    bits |= (__builtin_bit_cast(u32, v1.z) != 0u) ? 64u : 0u;
    bits |= (__builtin_bit_cast(u32, v1.w) != 0u) ? 128u : 0u;
    if ((n >> 3) == byteidx) bits |= 1u << (n & 7);
    bm[idx] = (u8)bits;
    // fused W prep (blocks 0..255)
    if (blockIdx.x < 256) {
        int c = blockIdx.x;
        int t = threadIdx.x;
        float v = W[c * HD + t];
        u16 hi = f2bf(v);
        float lo = v - bf2f(hi);
        WTh[t * Cc + c] = hi;
        WTl[t * Cc + c] = f2bf(lo);
    }
}

// ---- k1: Wx = x @ W via split-bf16 MFMA.
//      WxTt in MFMA-B tile layout:
//        offset(bh, n, d) = bh*65536 + (n>>5)*2048 + (d>>4)*512
//                           + ((n>>3)&3)*128 + (d&15)*8 + (n&7)
//      Fused epilogue computes exact fp32 ei/ej, PRE-SCALED by LOG2E. ----
__global__ __launch_bounds__(256) void k_gemm_xw(const float* __restrict__ x,
        const u16* __restrict__ WTh, const u16* __restrict__ WTl,
        const float* __restrict__ a, u16* __restrict__ WxTt,
        float* __restrict__ ei, float* __restrict__ ej) {
    int wave = blockIdx.x * 4 + (threadIdx.x >> 6);
    int lane = threadIdx.x & 63;
    int row_tile = wave >> 2;        // 0..511 over 8192 rows
    int h = wave & 3;                // 64-col group == head
    int m0 = row_tile * 16;
    int b = m0 >> 10;
    int nloc0 = m0 & 1023;
    int c15 = lane & 15;
    int quad = lane >> 4;

    f32x4 acc[4] = {};
    const float* xrow = x + (size_t)(m0 + c15) * Cc + quad * 8;
    #pragma unroll
    for (int k0 = 0; k0 < Cc; k0 += 32) {
        float4 xv0 = *reinterpret_cast<const float4*>(xrow + k0);
        float4 xv1 = *reinterpret_cast<const float4*>(xrow + k0 + 4);
        float xv[8] = {xv0.x, xv0.y, xv0.z, xv0.w, xv1.x, xv1.y, xv1.z, xv1.w};
        u16x8 xh, xl;
        #pragma unroll
        for (int i = 0; i < 8; ++i) {
            u16 hb = f2bf(xv[i]);
            xh[i] = hb;
            xl[i] = f2bf(xv[i] - bf2f(hb));
        }
        bf16x8 ah = __builtin_bit_cast(bf16x8, xh);
        bf16x8 al = __builtin_bit_cast(bf16x8, xl);
        #pragma unroll
        for (int t = 0; t < 4; ++t) {
            const u16* wb = WTh + (size_t)(h * 64 + t * 16 + c15) * Cc + k0 + quad * 8;
            const u16* wl = WTl + (size_t)(h * 64 + t * 16 + c15) * Cc + k0 + quad * 8;
            bf16x8 bh = *reinterpret_cast<const bf16x8*>(wb);
            bf16x8 bl = *reinterpret_cast<const bf16x8*>(wl);
            acc[t] = __builtin_amdgcn_mfma_f32_16x16x32_bf16(ah, bh, acc[t], 0, 0, 0);
            acc[t] = __builtin_amdgcn_mfma_f32_16x16x32_bf16(al, bh, acc[t], 0, 0, 0);
            acc[t] = __builtin_amdgcn_mfma_f32_16x16x32_bf16(ah, bl, acc[t], 0, 0, 0);
        }
    }
    int bh = b * Hh + h;
    int n_base = nloc0 + quad * 4;
    int chunk = nloc0 >> 5;
    int jq = ((n_base >> 3) & 3);
    int ii = n_base & 7;             // 0 or 4
    size_t tb = (size_t)bh * 65536 + chunk * 2048 + jq * 128 + c15 * 8 + ii;
    #pragma unroll
    for (int t = 0; t < 4; ++t) {
        u32 lo = (u32)f2bf(acc[t][0]) | ((u32)f2bf(acc[t][1]) << 16);
        u32 hi = (u32)f2bf(acc[t][2]) | ((u32)f2bf(acc[t][3]) << 16);
        uint2 pk; pk.x = lo; pk.y = hi;
        *reinterpret_cast<uint2*>(WxTt + tb + t * 512) = pk;
    }
    float ai[4], aj[4];
    #pragma unroll
    for (int t = 0; t < 4; ++t) {
        ai[t] = a[h * 2 * Dd + t * 16 + c15];
        aj[t] = a[h * 2 * Dd + Dd + t * 16 + c15];
    }
    #pragma unroll
    for (int r = 0; r < 4; ++r) {
        float si = acc[0][r] * ai[0] + acc[1][r] * ai[1] + acc[2][r] * ai[2] + acc[3][r] * ai[3];
        float sj = acc[0][r] * aj[0] + acc[1][r] * aj[1] + acc[2][r] * aj[2] + acc[3][r] * aj[3];
        #pragma unroll
        for (int off = 1; off < 16; off <<= 1) {
            si += __shfl_xor(si, off);
            sj += __shfl_xor(sj, off);
        }
        if (c15 == 0) {
            int n = nloc0 + quad * 4 + r;
            ei[(size_t)bh * Nn + n] = si * LOG2E;   // pre-scaled for exp2
            ej[(size_t)bh * Nn + n] = sj * LOG2E;
        }
    }
}

// ---- k2: out = softmax(e) @ Wx per (b,h).
//      Block = (bh, 32-row tile); 4 waves split j into quarters; LDS combine.
//      l computed by extra MFMAs vs ones-column B-fragment. ----
__global__ __launch_bounds__(256) void k_attn(const u8* __restrict__ bm,
        const u16* __restrict__ WxTt, const float* __restrict__ eis,
        const float* __restrict__ ejs, float* __restrict__ out) {
    int widx = threadIdx.x >> 6;     // j-quarter
    int lane = threadIdx.x & 63;
    int bh = blockIdx.x >> 5;        // 0..31
    int tile = blockIdx.x & 31;      // 32-row tile
    int b = bh >> 2, h = bh & 3;
    int n0 = tile * 32;
    int col = lane & 15;
    int quad = lane >> 4;

    int r0 = n0 + col, r1 = n0 + 16 + col;
    float ei0 = eis[(size_t)bh * Nn + r0];
    float ei1 = eis[(size_t)bh * Nn + r1];
    const u8* mb0 = bm + ((size_t)(b * Nn + r0)) * 128;
    const u8* mb1 = bm + ((size_t)(b * Nn + r1)) * 128;
    const float* ejrow = ejs + (size_t)bh * Nn + quad * 8;
    const u16* wxplane = WxTt + (size_t)bh * 65536 + lane * 8;

    // ones-column B fragment (col 0 holds bf16 1.0 across all k)
    u16 ov = (col == 0) ? (u16)0x3f80 : (u16)0;
    u16x8 onesu = {ov, ov, ov, ov, ov, ov, ov, ov};
    bf16x8 onesf = __builtin_bit_cast(bf16x8, onesu);

    f32x4 acc0[4] = {}, acc1[4] = {};
    f32x4 accl0 = {}, accl1 = {};
    int jbase = widx * 256;
    #pragma unroll 2
    for (int s = 0; s < 8; ++s) {
        int j0 = jbase + s * 32;
        u32 mw0 = *reinterpret_cast<const u32*>(mb0 + (j0 >> 3));
        u32 mw1 = *reinterpret_cast<const u32*>(mb1 + (j0 >> 3));
        u32 q0 = (mw0 >> (quad * 8)) & 0xffu;
        u32 q1 = (mw1 >> (quad * 8)) & 0xffu;
        float4 eA = *reinterpret_cast<const float4*>(ejrow + j0);
        float4 eB = *reinterpret_cast<const float4*>(ejrow + j0 + 4);
        float ejv[8] = {eA.x, eA.y, eA.z, eA.w, eB.x, eB.y, eB.z, eB.w};
        u32 p0[4], p1[4];
        #pragma unroll
        for (int pi = 0; pi < 4; ++pi) {
            float e_lo = ejv[2 * pi], e_hi = ejv[2 * pi + 1];
            // row block 0
            float sa = ei0 + e_lo, sb = ei0 + e_hi;
            sa = fmaxf(sa, 0.2f * sa); sb = fmaxf(sb, 0.2f * sb);
            u32 ua = __builtin_bit_cast(u32, fast_exp2(sa));
            u32 ub = __builtin_bit_cast(u32, fast_exp2(sb));
            u32 m0 = (((q0 >> (2 * pi)) & 1u) ? 0xffffu : 0u)
                   | (((q0 >> (2 * pi + 1)) & 1u) ? 0xffff0000u : 0u);
            p0[pi] = ((ua >> 16) | (ub & 0xffff0000u)) & m0;
            // row block 1
            float sc = ei1 + e_lo, sd = ei1 + e_hi;
            sc = fmaxf(sc, 0.2f * sc); sd = fmaxf(sd, 0.2f * sd);
            u32 uc = __builtin_bit_cast(u32, fast_exp2(sc));
            u32 ud = __builtin_bit_cast(u32, fast_exp2(sd));
            u32 m1 = (((q1 >> (2 * pi)) & 1u) ? 0xffffu : 0u)
                   | (((q1 >> (2 * pi + 1)) & 1u) ? 0xffff0000u : 0u);
            p1[pi] = ((uc >> 16) | (ud & 0xffff0000u)) & m1;
        }
        u32x4 pv0 = {p0[0], p0[1], p0[2], p0[3]};
        u32x4 pv1 = {p1[0], p1[1], p1[2], p1[3]};
        bf16x8 a0 = __builtin_bit_cast(bf16x8, pv0);
        bf16x8 a1 = __builtin_bit_cast(bf16x8, pv1);
        const u16* bbase = wxplane + (j0 >> 5) * 2048;
        #pragma unroll
        for (int t = 0; t < 4; ++t) {
            bf16x8 bfr = *reinterpret_cast<const bf16x8*>(bbase + t * 512);
            acc0[t] = __builtin_amdgcn_mfma_f32_16x16x32_bf16(a0, bfr, acc0[t], 0, 0, 0);
            acc1[t] = __builtin_amdgcn_mfma_f32_16x16x32_bf16(a1, bfr, acc1[t], 0, 0, 0);
        }
        accl0 = __builtin_amdgcn_mfma_f32_16x16x32_bf16(a0, onesf, accl0, 0, 0, 0);
        accl1 = __builtin_amdgcn_mfma_f32_16x16x32_bf16(a1, onesf, accl1, 0, 0, 0);
    }

    // ---- cross-wave combine in LDS ----
    __shared__ f32x4 lacc[4][8][64];      // 32 KiB
    __shared__ float lsums[4][2][16];
    #pragma unroll
    for (int t = 0; t < 4; ++t) {
        lacc[widx][t][lane] = acc0[t];
        lacc[widx][4 + t][lane] = acc1[t];
    }
    if (col == 0) {
        #pragma unroll
        for (int r = 0; r < 4; ++r) {
            lsums[widx][0][quad * 4 + r] = accl0[r];
            lsums[widx][1][quad * 4 + r] = accl1[r];
        }
    }
    __syncthreads();
    #pragma unroll
    for (int pp = 0; pp < 2; ++pp) {
        int p = widx * 2 + pp;
        int f = p >> 2, t = p & 3;
        f32x4 v = lacc[0][p][lane];
        v += lacc[1][p][lane];
        v += lacc[2][p][lane];
        v += lacc[3][p][lane];
        #pragma unroll
        for (int r = 0; r < 4; ++r) {
            int rloc = quad * 4 + r;
            float lv = lsums[0][f][rloc] + lsums[1][f][rloc]
                     + lsums[2][f][rloc] + lsums[3][f][rloc];
            int nr = n0 + f * 16 + rloc;
            out[(size_t)(b * Nn + nr) * HD + h * Dd + t * 16 + col] = v[r] * (1.0f / lv);
        }
    }
}

extern "C" void kernel_launch(void* const* d_in, const int* in_sizes, int n_in,
                              void* d_out, int out_size, void* d_ws, size_t ws_size,
                              hipStream_t stream) {
    const float* x   = (const float*)d_in[0];   // (8,1024,256) fp32
    const float* adj = (const float*)d_in[1];   // (8,1024,1024) fp32
    const float* W   = (const float*)d_in[2];   // (256,256) fp32
    const float* a   = (const float*)d_in[3];   // (1,4,128) fp32
    float* out = (float*)d_out;                 // (8,1024,256) fp32

    char* ws = (char*)d_ws;
    u16*   WTh  = (u16*)(ws);                                   // 128 KiB
    u16*   WTl  = (u16*)(ws + (128u << 10));                    // 128 KiB
    u16*   WxTt = (u16*)(ws + (256u << 10));                    // 4 MiB tile layout
    float* ei   = (float*)(ws + (256u << 10) + (4u << 20));     // 128 KiB
    float* ej   = (float*)(ws + (384u << 10) + (4u << 20));     // 128 KiB
    u8*    bm   = (u8*)(ws + (512u << 10) + (4u << 20));        // 1 MiB

    k_bitmask_prep<<<4096, 256, 0, stream>>>(adj, bm, W, WTh, WTl);
    k_gemm_xw<<<512, 256, 0, stream>>>(x, WTh, WTl, a, WxTt, ei, ej);
    k_attn<<<1024, 256, 0, stream>>>(bm, WxTt, ei, ej, out);
}

// Round 5
// 111.843 us; speedup vs baseline: 1.6618x; 1.1171x over previous
//
#include <hip/hip_runtime.h>

#define Nn 1024
#define Cc 256
#define Hh 4
#define Dd 64
#define HD 256
#define LOG2E 1.4426950408889634f
#define WSTRIDE 264   // u16 stride for LDS W tile: 528 B = 132 dwords -> bank-spread

typedef unsigned short u16;
typedef unsigned int u32;
typedef unsigned long long u64;
typedef unsigned char u8;
typedef __bf16 bf16x2 __attribute__((ext_vector_type(2)));
typedef __bf16 bf16x8 __attribute__((ext_vector_type(8)));
typedef float f32x4 __attribute__((ext_vector_type(4)));
typedef u16 u16x8 __attribute__((ext_vector_type(8)));
typedef u32 u32x4 __attribute__((ext_vector_type(4)));

__device__ __forceinline__ float bf2f(u16 v) {
    return __builtin_bit_cast(float, (u32)v << 16);
}
__device__ __forceinline__ u16 f2bf(float f) {
    u32 u = __builtin_bit_cast(u32, f);
    return (u16)((u + 0x7fffu + ((u >> 16) & 1u)) >> 16);
}
__device__ __forceinline__ u32 pk_bf16(float a, float b) {
#if __has_builtin(__builtin_amdgcn_cvt_pk_bf16_f32)
    bf16x2 v = __builtin_amdgcn_cvt_pk_bf16_f32(a, b);
    return __builtin_bit_cast(u32, v);
#else
    return (u32)f2bf(a) | ((u32)f2bf(b) << 16);
#endif
}
__device__ __forceinline__ float fast_exp2(float x) {
#if __has_builtin(__builtin_amdgcn_exp2f)
    return __builtin_amdgcn_exp2f(x);
#else
    float r; asm("v_exp_f32 %0, %1" : "=v"(r) : "v"(x)); return r;
#endif
}

// ---- k_fused: blocks <512 do x@W GEMM (W staged hi-only in LDS);
//      blocks >=512 build the adjacency byte-mask. Independent work. ----
__global__ __launch_bounds__(256) void k_fused(const float* __restrict__ adj,
        u8* __restrict__ bm, const float* __restrict__ x,
        const float* __restrict__ W, const float* __restrict__ a,
        u16* __restrict__ WxTt, float* __restrict__ ei, float* __restrict__ ej) {
    __shared__ u16 ldsw[Dd * WSTRIDE];   // 33.8 KiB

    if (blockIdx.x >= 512) {
        // ---- adjacency byte-mask (incl. diagonal) ----
        int idx = (blockIdx.x - 512) * 256 + threadIdx.x;   // 0 .. 1048575
        int bn = idx >> 7;
        int byteidx = idx & 127;
        int n = bn & 1023;
        const float* p = adj + ((size_t)bn << 10) + (byteidx << 3);
        float4 v0 = *reinterpret_cast<const float4*>(p);
        float4 v1 = *reinterpret_cast<const float4*>(p + 4);
        u32 bits = 0;
        bits |= (__builtin_bit_cast(u32, v0.x) != 0u) ? 1u : 0u;
        bits |= (__builtin_bit_cast(u32, v0.y) != 0u) ? 2u : 0u;
        bits |= (__builtin_bit_cast(u32, v0.z) != 0u) ? 4u : 0u;
        bits |= (__builtin_bit_cast(u32, v0.w) != 0u) ? 8u : 0u;
        bits |= (__builtin_bit_cast(u32, v1.x) != 0u) ? 16u : 0u;
        bits |= (__builtin_bit_cast(u32, v1.y) != 0u) ? 32u : 0u;
        bits |= (__builtin_bit_cast(u32, v1.z) != 0u) ? 64u : 0u;
        bits |= (__builtin_bit_cast(u32, v1.w) != 0u) ? 128u : 0u;
        if ((n >> 3) == byteidx) bits |= 1u << (n & 7);
        bm[idx] = (u8)bits;
        return;
    }

    // ---- GEMM part: block = (4 row-tiles, one h) ----
    int h = blockIdx.x & 3;
    int group = blockIdx.x >> 2;       // 0..127
    int tid = threadIdx.x;

    // stage W-hi for this h into LDS, transposed: ldsw[d][k], k fast.
    {
        const float* wrow = W + tid * HD + h * 64;   // row k = tid
        #pragma unroll
        for (int c = 0; c < 64; c += 4) {
            float4 wv = *reinterpret_cast<const float4*>(wrow + c);
            u32 p01 = pk_bf16(wv.x, wv.y);
            u32 p23 = pk_bf16(wv.z, wv.w);
            ldsw[(c + 0) * WSTRIDE + tid] = (u16)p01;
            ldsw[(c + 1) * WSTRIDE + tid] = (u16)(p01 >> 16);
            ldsw[(c + 2) * WSTRIDE + tid] = (u16)p23;
            ldsw[(c + 3) * WSTRIDE + tid] = (u16)(p23 >> 16);
        }
    }
    __syncthreads();

    int w = tid >> 6, lane = tid & 63;
    int row_tile = group * 4 + w;      // 0..511
    int m0 = row_tile * 16;
    int b = m0 >> 10;
    int nloc0 = m0 & 1023;
    int c15 = lane & 15;
    int quad = lane >> 4;

    f32x4 acc[4] = {};
    const float* xrow = x + (size_t)(m0 + c15) * Cc + quad * 8;
    #pragma unroll
    for (int k0 = 0; k0 < Cc; k0 += 32) {
        float4 xv0 = *reinterpret_cast<const float4*>(xrow + k0);
        float4 xv1 = *reinterpret_cast<const float4*>(xrow + k0 + 4);
        u32 h0 = pk_bf16(xv0.x, xv0.y);
        u32 h1 = pk_bf16(xv0.z, xv0.w);
        u32 h2 = pk_bf16(xv1.x, xv1.y);
        u32 h3 = pk_bf16(xv1.z, xv1.w);
        u32 l0 = pk_bf16(xv0.x - __builtin_bit_cast(float, h0 << 16),
                         xv0.y - __builtin_bit_cast(float, h0 & 0xffff0000u));
        u32 l1 = pk_bf16(xv0.z - __builtin_bit_cast(float, h1 << 16),
                         xv0.w - __builtin_bit_cast(float, h1 & 0xffff0000u));
        u32 l2 = pk_bf16(xv1.x - __builtin_bit_cast(float, h2 << 16),
                         xv1.y - __builtin_bit_cast(float, h2 & 0xffff0000u));
        u32 l3 = pk_bf16(xv1.z - __builtin_bit_cast(float, h3 << 16),
                         xv1.w - __builtin_bit_cast(float, h3 & 0xffff0000u));
        u32x4 hp = {h0, h1, h2, h3};
        u32x4 lp = {l0, l1, l2, l3};
        bf16x8 ah = __builtin_bit_cast(bf16x8, hp);
        bf16x8 al = __builtin_bit_cast(bf16x8, lp);
        const u16* ldsk = ldsw + k0 + quad * 8;
        #pragma unroll
        for (int t = 0; t < 4; ++t) {
            bf16x8 bh = *reinterpret_cast<const bf16x8*>(ldsk + (t * 16 + c15) * WSTRIDE);
            acc[t] = __builtin_amdgcn_mfma_f32_16x16x32_bf16(ah, bh, acc[t], 0, 0, 0);
            acc[t] = __builtin_amdgcn_mfma_f32_16x16x32_bf16(al, bh, acc[t], 0, 0, 0);
        }
    }
    int bh = b * Hh + h;
    // WxTt tile layout: offset(bh,n,d) = bh*65536 + (n>>5)*2048 + (d>>4)*512
    //                   + ((n>>3)&3)*128 + (d&15)*8 + (n&7)
    int n_base = nloc0 + quad * 4;
    int chunk = nloc0 >> 5;
    int jq = ((n_base >> 3) & 3);
    int ii = n_base & 7;               // 0 or 4
    size_t tb = (size_t)bh * 65536 + chunk * 2048 + jq * 128 + c15 * 8 + ii;
    #pragma unroll
    for (int t = 0; t < 4; ++t) {
        uint2 pk2;
        pk2.x = pk_bf16(acc[t][0], acc[t][1]);
        pk2.y = pk_bf16(acc[t][2], acc[t][3]);
        *reinterpret_cast<uint2*>(WxTt + tb + t * 512) = pk2;
    }
    // ei/ej epilogue (pre-scaled by LOG2E for exp2)
    float ai[4], aj[4];
    #pragma unroll
    for (int t = 0; t < 4; ++t) {
        ai[t] = a[h * 2 * Dd + t * 16 + c15];
        aj[t] = a[h * 2 * Dd + Dd + t * 16 + c15];
    }
    #pragma unroll
    for (int r = 0; r < 4; ++r) {
        float si = acc[0][r] * ai[0] + acc[1][r] * ai[1] + acc[2][r] * ai[2] + acc[3][r] * ai[3];
        float sj = acc[0][r] * aj[0] + acc[1][r] * aj[1] + acc[2][r] * aj[2] + acc[3][r] * aj[3];
        #pragma unroll
        for (int off = 1; off < 16; off <<= 1) {
            si += __shfl_xor(si, off);
            sj += __shfl_xor(sj, off);
        }
        if (c15 == 0) {
            int n = nloc0 + quad * 4 + r;
            ei[(size_t)bh * Nn + n] = si * LOG2E;
            ej[(size_t)bh * Nn + n] = sj * LOG2E;
        }
    }
}

// ---- k_attn: out = softmax(e) @ Wx per (b,h).
//      Block = (bh, 32-row tile); 4 waves split j into quarters; LDS combine.
//      l via extra MFMAs vs ones-column B-fragment. ----
__global__ __launch_bounds__(256) void k_attn(const u8* __restrict__ bm,
        const u16* __restrict__ WxTt, const float* __restrict__ eis,
        const float* __restrict__ ejs, float* __restrict__ out) {
    int widx = threadIdx.x >> 6;     // j-quarter
    int lane = threadIdx.x & 63;
    int bh = blockIdx.x >> 5;        // 0..31
    int tile = blockIdx.x & 31;      // 32-row tile
    int b = bh >> 2, h = bh & 3;
    int n0 = tile * 32;
    int col = lane & 15;
    int quad = lane >> 4;

    int r0 = n0 + col, r1 = n0 + 16 + col;
    float ei0 = eis[(size_t)bh * Nn + r0];
    float ei1 = eis[(size_t)bh * Nn + r1];
    const u8* mb0 = bm + ((size_t)(b * Nn + r0)) * 128;
    const u8* mb1 = bm + ((size_t)(b * Nn + r1)) * 128;
    const float* ejrow = ejs + (size_t)bh * Nn + quad * 8;
    const u16* wxplane = WxTt + (size_t)bh * 65536 + lane * 8;

    u16 ov = (col == 0) ? (u16)0x3f80 : (u16)0;
    u16x8 onesu = {ov, ov, ov, ov, ov, ov, ov, ov};
    bf16x8 onesf = __builtin_bit_cast(bf16x8, onesu);

    f32x4 acc0[4] = {}, acc1[4] = {};
    f32x4 accl0 = {}, accl1 = {};
    int jbase = widx * 256;
    #pragma unroll 2
    for (int s = 0; s < 8; ++s) {
        int j0 = jbase + s * 32;
        u32 mw0 = *reinterpret_cast<const u32*>(mb0 + (j0 >> 3));
        u32 mw1 = *reinterpret_cast<const u32*>(mb1 + (j0 >> 3));
        u32 q0 = (mw0 >> (quad * 8)) & 0xffu;
        u32 q1 = (mw1 >> (quad * 8)) & 0xffu;
        float4 eA = *reinterpret_cast<const float4*>(ejrow + j0);
        float4 eB = *reinterpret_cast<const float4*>(ejrow + j0 + 4);
        float ejv[8] = {eA.x, eA.y, eA.z, eA.w, eB.x, eB.y, eB.z, eB.w};
        u32 p0[4], p1[4];
        #pragma unroll
        for (int pi = 0; pi < 4; ++pi) {
            float e_lo = ejv[2 * pi], e_hi = ejv[2 * pi + 1];
            float sa = ei0 + e_lo, sb = ei0 + e_hi;
            sa = fmaxf(sa, 0.2f * sa); sb = fmaxf(sb, 0.2f * sb);
            u32 m0 = (((q0 >> (2 * pi)) & 1u) ? 0xffffu : 0u)
                   | (((q0 >> (2 * pi + 1)) & 1u) ? 0xffff0000u : 0u);
            p0[pi] = pk_bf16(fast_exp2(sa), fast_exp2(sb)) & m0;
            float sc = ei1 + e_lo, sd = ei1 + e_hi;
            sc = fmaxf(sc, 0.2f * sc); sd = fmaxf(sd, 0.2f * sd);
            u32 m1 = (((q1 >> (2 * pi)) & 1u) ? 0xffffu : 0u)
                   | (((q1 >> (2 * pi + 1)) & 1u) ? 0xffff0000u : 0u);
            p1[pi] = pk_bf16(fast_exp2(sc), fast_exp2(sd)) & m1;
        }
        u32x4 pv0 = {p0[0], p0[1], p0[2], p0[3]};
        u32x4 pv1 = {p1[0], p1[1], p1[2], p1[3]};
        bf16x8 a0 = __builtin_bit_cast(bf16x8, pv0);
        bf16x8 a1 = __builtin_bit_cast(bf16x8, pv1);
        const u16* bbase = wxplane + (j0 >> 5) * 2048;
        #pragma unroll
        for (int t = 0; t < 4; ++t) {
            bf16x8 bfr = *reinterpret_cast<const bf16x8*>(bbase + t * 512);
            acc0[t] = __builtin_amdgcn_mfma_f32_16x16x32_bf16(a0, bfr, acc0[t], 0, 0, 0);
            acc1[t] = __builtin_amdgcn_mfma_f32_16x16x32_bf16(a1, bfr, acc1[t], 0, 0, 0);
        }
        accl0 = __builtin_amdgcn_mfma_f32_16x16x32_bf16(a0, onesf, accl0, 0, 0, 0);
        accl1 = __builtin_amdgcn_mfma_f32_16x16x32_bf16(a1, onesf, accl1, 0, 0, 0);
    }

    __shared__ f32x4 lacc[4][8][64];      // 32 KiB
    __shared__ float lsums[4][2][16];
    #pragma unroll
    for (int t = 0; t < 4; ++t) {
        lacc[widx][t][lane] = acc0[t];
        lacc[widx][4 + t][lane] = acc1[t];
    }
    if (col == 0) {
        #pragma unroll
        for (int r = 0; r < 4; ++r) {
            lsums[widx][0][quad * 4 + r] = accl0[r];
            lsums[widx][1][quad * 4 + r] = accl1[r];
        }
    }
    __syncthreads();
    #pragma unroll
    for (int pp = 0; pp < 2; ++pp) {
        int p = widx * 2 + pp;
        int f = p >> 2, t = p & 3;
        f32x4 v = lacc[0][p][lane];
        v += lacc[1][p][lane];
        v += lacc[2][p][lane];
        v += lacc[3][p][lane];
        #pragma unroll
        for (int r = 0; r < 4; ++r) {
            int rloc = quad * 4 + r;
            float lv = lsums[0][f][rloc] + lsums[1][f][rloc]
                     + lsums[2][f][rloc] + lsums[3][f][rloc];
            int nr = n0 + f * 16 + rloc;
            out[(size_t)(b * Nn + nr) * HD + h * Dd + t * 16 + col] = v[r] * (1.0f / lv);
        }
    }
}

extern "C" void kernel_launch(void* const* d_in, const int* in_sizes, int n_in,
                              void* d_out, int out_size, void* d_ws, size_t ws_size,
                              hipStream_t stream) {
    const float* x   = (const float*)d_in[0];   // (8,1024,256) fp32
    const float* adj = (const float*)d_in[1];   // (8,1024,1024) fp32
    const float* W   = (const float*)d_in[2];   // (256,256) fp32
    const float* a   = (const float*)d_in[3];   // (1,4,128) fp32
    float* out = (float*)d_out;                 // (8,1024,256) fp32

    char* ws = (char*)d_ws;
    u16*   WxTt = (u16*)(ws);                           // 4 MiB tile layout
    float* ei   = (float*)(ws + (4u << 20));            // 128 KiB
    float* ej   = (float*)(ws + (4u << 20) + (128u << 10));   // 128 KiB
    u8*    bm   = (u8*)(ws + (4u << 20) + (256u << 10));      // 1 MiB

    k_fused<<<4608, 256, 0, stream>>>(adj, bm, x, W, a, WxTt, ei, ej);
    k_attn<<<1024, 256, 0, stream>>>(bm, WxTt, ei, ej, out);
}